// Round 2
// baseline (7978.000 us; speedup 1.0000x reference)
//
#include <hip/hip_runtime.h>
#include <hip/hip_cooperative_groups.h>

namespace cg = cooperative_groups;

#define N_NODES 8192
#define DEGREE 32
#define D_FEAT 256
#define F4 (D_FEAT / 4)     // 64 float4 per row
#define NBLOCKS 1024
#define RPB 8               // rows per block (4 waves x 2 sub-iters)

// One cooperative kernel:
//   phase 0: each block loads its 8 rows' edges (exactly 256 = blockDim),
//            row-normalizes via 32-lane shuffle reduce, stores dst/w in LDS
//            (stays resident for all 32 iterations).
//   loop k=1..32: y = A @ x (1 KB coalesced gather per edge per wave),
//            tap accumulate into registers at k in {1,2,4,8,16,32},
//            grid-wide sync, ping-pong x/y.
//   epilogue: write register tap-accumulator to out.
__global__ __launch_bounds__(256) void diffuse_kernel(
    const int* __restrict__ dst, const float* __restrict__ e,
    const float* __restrict__ h, float* __restrict__ out,
    float* __restrict__ buf0, float* __restrict__ buf1) {
  __shared__ int   s_dst[RPB][DEGREE];
  __shared__ float s_w[RPB][DEGREE];

  const int tid = threadIdx.x;
  const int b = blockIdx.x;
  cg::grid_group grid = cg::this_grid();

  // ---- phase 0: block-local edge load + row normalize (rows are 32-aligned) ----
  {
    int eidx = b * (RPB * DEGREE) + tid;   // 256 edges per block, 1 per thread
    float v = e[eidx];
    float s = v;
    for (int m = 1; m < 32; m <<= 1) s += __shfl_xor(s, m, 32);
    int rl = tid >> 5, j = tid & 31;
    s_w[rl][j]   = v / s;
    s_dst[rl][j] = dst[eidx] * F4;         // pre-scaled to float4 row offset
  }
  __syncthreads();

  const int wave = tid >> 6;   // 0..3
  const int f    = tid & 63;   // float4 column

  const float4* xin = (const float4*)h;
  float4* ycur  = (float4*)buf0;
  float4* ynext = (float4*)buf1;

  float4 accout0 = make_float4(0.f, 0.f, 0.f, 0.f);
  float4 accout1 = make_float4(0.f, 0.f, 0.f, 0.f);

  for (int k = 1; k <= 32; ++k) {
    // uniform scalar coefficient for this iteration (0 = no tap)
    float coef = 0.f;
    if (k <= 2)       coef = 1.f;
    else if (k == 4)  coef = 1.f / 2.f;
    else if (k == 8)  coef = 1.f / 6.f;
    else if (k == 16) coef = 1.f / 24.f;
    else if (k == 32) coef = 1.f / 120.f;

#pragma unroll
    for (int s = 0; s < 2; ++s) {
      const int rl = wave + 4 * s;         // local row 0..7
      float4 acc = make_float4(0.f, 0.f, 0.f, 0.f);
#pragma unroll
      for (int j = 0; j < DEGREE; ++j) {
        float  wj = s_w[rl][j];            // LDS broadcast
        float4 v  = xin[s_dst[rl][j] + f]; // coalesced 1 KB wave gather
        acc.x += wj * v.x;
        acc.y += wj * v.y;
        acc.z += wj * v.z;
        acc.w += wj * v.w;
      }
      ycur[(b * RPB + rl) * F4 + f] = acc;
      if (coef != 0.f) {
        if (s == 0) {
          accout0.x += coef * acc.x; accout0.y += coef * acc.y;
          accout0.z += coef * acc.z; accout0.w += coef * acc.w;
        } else {
          accout1.x += coef * acc.x; accout1.y += coef * acc.y;
          accout1.z += coef * acc.z; accout1.w += coef * acc.w;
        }
      }
    }

    __threadfence();   // device-scope release: cross-XCD visibility of y
    grid.sync();

    xin = (const float4*)ycur;
    float4* t = ycur; ycur = ynext; ynext = t;   // explicit swap (no dyn index)
  }

  // ---- epilogue: write tap accumulators ----
  ((float4*)out)[(b * RPB + wave + 0) * F4 + f] = accout0;
  ((float4*)out)[(b * RPB + wave + 4) * F4 + f] = accout1;
}

extern "C" void kernel_launch(void* const* d_in, const int* in_sizes, int n_in,
                              void* d_out, int out_size, void* d_ws, size_t ws_size,
                              hipStream_t stream) {
  // inputs: src (unused — structure known), dst (int32), e (f32), h (f32)
  const int*   dst = (const int*)d_in[1];
  const float* e   = (const float*)d_in[2];
  const float* h   = (const float*)d_in[3];
  float* out = (float*)d_out;

  char* ws = (char*)d_ws;
  float* buf0 = (float*)ws;                        // 8 MB
  float* buf1 = (float*)(ws + (size_t)(8u << 20)); // 8 MB

  void* args[] = {(void*)&dst, (void*)&e, (void*)&h,
                  (void*)&out, (void*)&buf0, (void*)&buf1};
  hipLaunchCooperativeKernel((void*)diffuse_kernel, dim3(NBLOCKS), dim3(256),
                             args, 0, stream);
}

// Round 3
// 508.070 us; speedup vs baseline: 15.7026x; 15.7026x over previous
//
#include <hip/hip_runtime.h>

#define N_NODES 8192
#define DEGREE 32
#define D_FEAT 256
#define SLICE_F 64                    // features per slice
#define N_SLICES (D_FEAT / SLICE_F)   // 4 slices of 2 MB each
#define RPB 4                         // rows per block (1 per wave)

// y = A @ x in feature-sliced layout.
// Layout of x/y buffers: [N_SLICES][N_NODES][SLICE_F] (each slice 2 MB).
// slice is tied to an XCD pair via blockIdx%8 so each XCD's gather working
// set (its 2 MB slice) stays L2-resident.
// Each block: 4 waves, one row per wave, 64 lanes = 64 features (1 float).
// Edge staging re-normalizes from e on the fly (32-lane shuffle reduce).
// MODE: 0 = y only; 1 = out = coef*acc (init); 2 = out += coef*acc.
template <int MODE>
__global__ __launch_bounds__(256) void spmm_kernel(
    const int* __restrict__ dst, const float* __restrict__ e,
    const float* __restrict__ xbase, int xstride, int slice_off,
    float* __restrict__ y, float* __restrict__ out, float coef) {
  __shared__ int   s_dst[RPB][DEGREE];
  __shared__ float s_w[RPB][DEGREE];

  const int tid = threadIdx.x;
  const int b   = blockIdx.x;
  const int slice = (b & 7) >> 1;                 // XCD pair -> slice
  const int wb    = ((b >> 3) << 1) | (b & 1);    // within-slice block [0,2048)
  const int row_base = wb * RPB;

  // ---- stage + normalize this block's 128 edges (rows are 32-aligned) ----
  if (tid < RPB * DEGREE) {
    int rl = tid >> 5, j = tid & 31;
    int eidx = (row_base + rl) * DEGREE + j;
    float v = e[eidx];
    float s = v;
    for (int m = 1; m < 32; m <<= 1) s += __shfl_xor(s, m, 32);
    s_w[rl][j]   = v / s;
    s_dst[rl][j] = dst[eidx] * xstride;   // pre-scaled gather offset
  }
  __syncthreads();

  const int wave = tid >> 6;   // row within block
  const int f    = tid & 63;   // feature within slice

  const float* __restrict__ x = xbase + (size_t)slice * slice_off;

  float acc = 0.f;
#pragma unroll
  for (int j = 0; j < DEGREE; ++j) {
    acc += s_w[wave][j] * x[s_dst[wave][j] + f];   // 256 B coalesced, L2-hot
  }

  const int row = row_base + wave;
  y[((size_t)slice * N_NODES + row) * SLICE_F + f] = acc;

  if (MODE) {
    const int oidx = row * D_FEAT + slice * SLICE_F + f;  // row-major out
    if (MODE == 1) out[oidx] = coef * acc;
    else           out[oidx] += coef * acc;
  }
}

extern "C" void kernel_launch(void* const* d_in, const int* in_sizes, int n_in,
                              void* d_out, int out_size, void* d_ws, size_t ws_size,
                              hipStream_t stream) {
  // inputs: src (unused — structure known), dst (int32), e (f32), h (f32)
  const int*   dst = (const int*)d_in[1];
  const float* e   = (const float*)d_in[2];
  const float* h   = (const float*)d_in[3];
  float* out = (float*)d_out;

  char* ws = (char*)d_ws;
  float* buf0 = (float*)ws;                        // 8 MB sliced x
  float* buf1 = (float*)(ws + (size_t)(8u << 20)); // 8 MB sliced y

  const int NB = N_SLICES * (N_NODES / RPB) ;      // 4 * 2048 = 8192 blocks

  float* bufs[2] = {buf0, buf1};
  int pb = 0;
  const float* xin = h;

  for (int k = 1; k <= 32; ++k) {
    float* y = bufs[pb];
    // first iteration gathers from row-major h; later from sliced buffers
    int xstride   = (k == 1) ? D_FEAT : SLICE_F;
    int slice_off = (k == 1) ? SLICE_F : N_NODES * SLICE_F;

    float coef; int mode;
    switch (k) {
      case 1:  coef = 1.f;         mode = 1; break;
      case 2:  coef = 1.f;         mode = 2; break;
      case 4:  coef = 1.f / 2.f;   mode = 2; break;
      case 8:  coef = 1.f / 6.f;   mode = 2; break;
      case 16: coef = 1.f / 24.f;  mode = 2; break;
      case 32: coef = 1.f / 120.f; mode = 2; break;
      default: coef = 0.f;         mode = 0; break;
    }

    if (mode == 0)
      spmm_kernel<0><<<NB, 256, 0, stream>>>(dst, e, xin, xstride, slice_off, y, out, coef);
    else if (mode == 1)
      spmm_kernel<1><<<NB, 256, 0, stream>>>(dst, e, xin, xstride, slice_off, y, out, coef);
    else
      spmm_kernel<2><<<NB, 256, 0, stream>>>(dst, e, xin, xstride, slice_off, y, out, coef);

    xin = y;
    pb ^= 1;
  }
}

// Round 5
// 482.543 us; speedup vs baseline: 16.5332x; 1.0529x over previous
//
#include <hip/hip_runtime.h>

#define N_NODES 8192
#define DEGREE 32
#define D_FEAT 256
#define SLICE_F 64                    // features per slice
#define N_SLICES (D_FEAT / SLICE_F)   // 4 slices; bf16 slice = 1 MB
#define RPB 4                         // rows per block (1 per wave)

// bf16 <-> f32 helpers (round-to-nearest-even on the way down)
__device__ __forceinline__ float bf2f(unsigned short u) {
  union { unsigned int i; float f; } c;
  c.i = ((unsigned int)u) << 16;
  return c.f;
}
__device__ __forceinline__ unsigned short f2bf(float x) {
  union { float f; unsigned int i; } c;
  c.f = x;
  unsigned int r = c.i + 0x7FFFu + ((c.i >> 16) & 1u);
  return (unsigned short)(r >> 16);
}

// y = A @ x, feature-sliced, iterate stored bf16, all math f32.
// x/y layout: [N_SLICES][N_NODES][SLICE_F] bf16 (1 MB per slice).
// slice tied to XCD pair via blockIdx%8 -> per-XCD L2-resident working set.
// FIRST: read f32 row-major h instead of bf16 sliced buffer (iteration 1).
// MODE: 0 = y only; 1 = out = coef*acc (init); 2 = out += coef*acc.
// Taps accumulate from the f32 accumulator BEFORE bf16 rounding.
template <int MODE, int FIRST>
__global__ __launch_bounds__(256) void spmm_kernel(
    const int* __restrict__ dst, const float* __restrict__ e,
    const float* __restrict__ hx, const unsigned short* __restrict__ xb,
    unsigned short* __restrict__ y, float* __restrict__ out, float coef) {
  __shared__ int   s_dst[RPB][DEGREE];
  __shared__ float s_w[RPB][DEGREE];

  const int tid = threadIdx.x;
  const int b   = blockIdx.x;
  const int slice = (b & 7) >> 1;                 // XCD pair -> slice
  const int wb    = ((b >> 3) << 1) | (b & 1);    // within-slice block [0,2048)
  const int row_base = wb * RPB;

  // ---- stage + normalize this block's 128 edges (rows are 32-aligned) ----
  if (tid < RPB * DEGREE) {
    int rl = tid >> 5, j = tid & 31;
    int eidx = (row_base + rl) * DEGREE + j;
    float v = e[eidx];
    float s = v;
    for (int m = 1; m < 32; m <<= 1) s += __shfl_xor(s, m, 32);
    s_w[rl][j]   = v / s;
    s_dst[rl][j] = dst[eidx] * (FIRST ? D_FEAT : SLICE_F);  // gather offset
  }
  __syncthreads();

  const int wave = tid >> 6;   // row within block
  const int f    = tid & 63;   // feature within slice

  float acc = 0.f;
  if (FIRST) {
    const float* __restrict__ x = hx + slice * SLICE_F;
#pragma unroll
    for (int j = 0; j < DEGREE; ++j)
      acc += s_w[wave][j] * x[s_dst[wave][j] + f];          // 256 B/wave f32
  } else {
    const unsigned short* __restrict__ x =
        xb + (size_t)slice * (N_NODES * SLICE_F);
#pragma unroll
    for (int j = 0; j < DEGREE; ++j)
      acc += s_w[wave][j] * bf2f(x[s_dst[wave][j] + f]);    // 128 B/wave bf16
  }

  const int row = row_base + wave;
  y[((size_t)slice * N_NODES + row) * SLICE_F + f] = f2bf(acc);

  if (MODE) {
    const int oidx = row * D_FEAT + slice * SLICE_F + f;    // row-major f32 out
    if (MODE == 1) out[oidx] = coef * acc;
    else           out[oidx] += coef * acc;
  }
}

extern "C" void kernel_launch(void* const* d_in, const int* in_sizes, int n_in,
                              void* d_out, int out_size, void* d_ws, size_t ws_size,
                              hipStream_t stream) {
  // inputs: src (unused — structure known), dst (int32), e (f32), h (f32)
  const int*   dst = (const int*)d_in[1];
  const float* e   = (const float*)d_in[2];
  const float* h   = (const float*)d_in[3];
  float* out = (float*)d_out;

  char* ws = (char*)d_ws;
  unsigned short* buf0 = (unsigned short*)ws;                       // 4 MB
  unsigned short* buf1 = (unsigned short*)(ws + (size_t)(4u << 20)); // 4 MB

  const int NB = N_SLICES * (N_NODES / RPB);   // 8192 blocks

  unsigned short* bufs[2] = {buf0, buf1};
  int pb = 0;
  const unsigned short* xin = buf0;  // unused on FIRST

  for (int k = 1; k <= 32; ++k) {
    unsigned short* y = bufs[pb];

    float coef; int mode;
    switch (k) {
      case 1:  coef = 1.f;         mode = 1; break;
      case 2:  coef = 1.f;         mode = 2; break;
      case 4:  coef = 1.f / 2.f;   mode = 2; break;
      case 8:  coef = 1.f / 6.f;   mode = 2; break;
      case 16: coef = 1.f / 24.f;  mode = 2; break;
      case 32: coef = 1.f / 120.f; mode = 2; break;
      default: coef = 0.f;         mode = 0; break;
    }

    if (k == 1)
      spmm_kernel<1, 1><<<NB, 256, 0, stream>>>(dst, e, h, xin, y, out, coef);
    else if (mode == 0)
      spmm_kernel<0, 0><<<NB, 256, 0, stream>>>(dst, e, h, xin, y, out, coef);
    else
      spmm_kernel<2, 0><<<NB, 256, 0, stream>>>(dst, e, h, xin, y, out, coef);

    xin = y;
    pb ^= 1;
  }
}